// Round 1
// baseline (1368.275 us; speedup 1.0000x reference)
//
#include <hip/hip_runtime.h>
#include <hip/hip_bf16.h>
#include <hip/hip_fp16.h>

typedef _Float16 half8 __attribute__((ext_vector_type(8)));
typedef float floatx4 __attribute__((ext_vector_type(4)));

__device__ __forceinline__ _Float16 f2h(float f) { return (_Float16)f; }

// ---------------------------------------------------------------------------
// setup: transpose + fp32->fp16 weight prep.  W [K,128] -> out [128,KPAD] f16
// ---------------------------------------------------------------------------
__global__ void wprep_kernel(const float* __restrict__ W, _Float16* __restrict__ out,
                             int K, int KPAD)
{
    int idx = blockIdx.x * 256 + threadIdx.x;
    if (idx >= 128 * KPAD) return;
    int j = idx / KPAD, k = idx % KPAD;
    float v = (k < K) ? W[(size_t)k * 128 + j] : 0.0f;
    out[idx] = f2h(v);
}

// h0 = emb[gate_type]  ->  f16 [N,64]
__global__ void embed_kernel(const int* __restrict__ gt, const float* __restrict__ emb,
                             _Float16* __restrict__ h0, int N)
{
    int idx = blockIdx.x * 256 + threadIdx.x;   // one float4 per thread
    if (idx >= N * 16) return;
    int i = idx >> 4, c4 = (idx & 15) * 4;
    floatx4 v = *(const floatx4*)(emb + (size_t)gt[i] * 64 + c4);
    _Float16* o = h0 + (size_t)i * 64 + c4;
    o[0] = f2h(v.x); o[1] = f2h(v.y); o[2] = f2h(v.z); o[3] = f2h(v.w);
}

// ---------------------------------------------------------------------------
// Edge kernel: t = relu(cat(h[src],w) @ W1 + b1); atomic scatter-add to hN[dst]
// One 16-edge x 128-col MFMA tile per wave iteration. A from global, B from LDS.
// ---------------------------------------------------------------------------
template<int KH>   // 64 (layer 0) or 128
__global__ void __launch_bounds__(256, 3)
edge_kernel(const _Float16* __restrict__ hA,   // [N,KH]
            const _Float16* __restrict__ W1T,  // [128,KPAD]
            const float* __restrict__ b1,      // [128]
            const int* __restrict__ src, const int* __restrict__ dst,
            const float* __restrict__ wE,      // [E,3]
            float* __restrict__ hN,            // [N,128] (atomic accum)
            int E, int numTiles)
{
    constexpr int KPAD = KH + 32;            // 96 or 160 (last chunk holds w)
    constexpr int KC   = KPAD / 32;          // 3 or 5 K-chunks
    constexpr int SPR  = KPAD / 8;           // raw 16B segments per row
    constexpr int LDSK = (KPAD + 63) & ~63;  // 128 or 192 (xor-swizzle closure)
    __shared__ __align__(16) _Float16 lds[128 * LDSK];

    const int tid = threadIdx.x;
    for (int s = tid; s < 128 * SPR; s += 256) {
        const int row = s / SPR, seg = s % SPR;
        half8 v = *(const half8*)(W1T + (size_t)row * KPAD + seg * 8);
        *(half8*)(&lds[row * LDSK + ((seg ^ (row & 7)) * 8)]) = v;
    }
    __syncthreads();

    const int lane = tid & 63;
    const int wv   = tid >> 6;
    const int lRow = lane & 15;   // A-row / B-col / D-col within tile
    const int lGrp = lane >> 4;   // k-group; D rows lGrp*4..+3

    float b1v[8];
#pragma unroll
    for (int jt = 0; jt < 8; ++jt) b1v[jt] = b1[jt * 16 + lRow];

    for (int tile = blockIdx.x * 4 + wv; tile < numTiles; tile += gridDim.x * 4) {
        const int e0 = tile * 16;
        int eA = e0 + lRow; if (eA >= E) eA = E - 1;
        const int s_ = src[eA];

        half8 afrag[KC];
#pragma unroll
        for (int kc = 0; kc < KC - 1; ++kc)
            afrag[kc] = *(const half8*)(hA + (size_t)s_ * KH + kc * 32 + lGrp * 8);
        {
            half8 aw;
#pragma unroll
            for (int i = 0; i < 8; ++i) aw[i] = (_Float16)0.0f;
            if (lGrp == 0) {
                aw[0] = f2h(wE[(size_t)eA * 3 + 0]);
                aw[1] = f2h(wE[(size_t)eA * 3 + 1]);
                aw[2] = f2h(wE[(size_t)eA * 3 + 2]);
            }
            afrag[KC - 1] = aw;
        }

        floatx4 acc[8] = {};
#pragma unroll
        for (int jt = 0; jt < 8; ++jt) {
            const int rb = (jt * 16 + lRow) * LDSK;
            const int sw = (jt * 16 + lRow) & 7;
#pragma unroll
            for (int kc = 0; kc < KC; ++kc) {
                const int seg = kc * 4 + lGrp;
                half8 bfrag = *(const half8*)(&lds[rb + ((seg ^ sw) * 8)]);
                acc[jt] = __builtin_amdgcn_mfma_f32_16x16x32_f16(afrag[kc], bfrag, acc[jt], 0, 0, 0);
            }
        }

#pragma unroll
        for (int r = 0; r < 4; ++r) {
            const int er = e0 + lGrp * 4 + r;
            if (er < E) {
                const int d_ = dst[er];
                float* dp = hN + (size_t)d_ * 128 + lRow;
#pragma unroll
                for (int jt = 0; jt < 8; ++jt) {
                    float v = acc[jt][r] + b1v[jt];
                    if (v > 0.0f) unsafeAtomicAdd(dp + jt * 16, v);  // relu-0 adds skipped
                }
            }
        }
    }
}

// ---------------------------------------------------------------------------
// Node kernel: h = normalize(relu(cat(h,hN) @ W2)); readout segment-sum.
// ---------------------------------------------------------------------------
template<int KH, bool LAST>   // KH = 64 or 128; K2 = KH+128
__global__ void __launch_bounds__(256, 2)
node_kernel(const _Float16* __restrict__ hA,   // [N,KH]
            const float* __restrict__ hN,      // [N,128]
            const _Float16* __restrict__ W2T,  // [128,K2]
            const int* __restrict__ n2g,
            _Float16* __restrict__ hOut,       // [N,128] (if !LAST)
            float* __restrict__ fOut,          // final h fp32 (if LAST; aliases hN)
            float* __restrict__ readout,       // [G,384], this layer at +layerOff
            int N, int numTiles, int layerOff)
{
    constexpr int K2  = KH + 128;   // 192 or 256
    constexpr int KCA = KH / 32;
    constexpr int KC  = K2 / 32;    // 6 or 8
    constexpr int SPR = K2 / 8;
    __shared__ __align__(16) _Float16 lds[128 * K2];

    const int tid = threadIdx.x;
    for (int s = tid; s < 128 * SPR; s += 256) {
        const int row = s / SPR, seg = s % SPR;
        half8 v = *(const half8*)(W2T + (size_t)row * K2 + seg * 8);
        *(half8*)(&lds[row * K2 + ((seg ^ (row & 7)) * 8)]) = v;
    }
    __syncthreads();

    const int lane = tid & 63;
    const int wv   = tid >> 6;
    const int lRow = lane & 15;
    const int lGrp = lane >> 4;

    for (int tile = blockIdx.x * 4 + wv; tile < numTiles; tile += gridDim.x * 4) {
        const int i0 = tile * 16;
        int iA = i0 + lRow; if (iA >= N) iA = N - 1;

        half8 afrag[KC];
#pragma unroll
        for (int kc = 0; kc < KCA; ++kc)
            afrag[kc] = *(const half8*)(hA + (size_t)iA * KH + kc * 32 + lGrp * 8);
#pragma unroll
        for (int kc = KCA; kc < KC; ++kc) {
            const float* p = hN + (size_t)iA * 128 + (kc - KCA) * 32 + lGrp * 8;
            floatx4 f0 = *(const floatx4*)(p);
            floatx4 f1 = *(const floatx4*)(p + 4);
            half8 a;
#pragma unroll
            for (int i = 0; i < 4; ++i) { a[i] = f2h(f0[i]); a[i + 4] = f2h(f1[i]); }
            afrag[kc] = a;
        }

        floatx4 acc[8] = {};
#pragma unroll
        for (int jt = 0; jt < 8; ++jt) {
            const int rb = (jt * 16 + lRow) * K2;
            const int sw = (jt * 16 + lRow) & 7;
#pragma unroll
            for (int kc = 0; kc < KC; ++kc) {
                const int seg = kc * 4 + lGrp;
                half8 bfrag = *(const half8*)(&lds[rb + ((seg ^ sw) * 8)]);
                acc[jt] = __builtin_amdgcn_mfma_f32_16x16x32_f16(afrag[kc], bfrag, acc[jt], 0, 0, 0);
            }
        }

        // relu + per-row L2 norm (rows live across the 16 lanes sharing lGrp)
        float scl[4];
#pragma unroll
        for (int r = 0; r < 4; ++r) {
            float s = 0.f;
#pragma unroll
            for (int jt = 0; jt < 8; ++jt) {
                float v = fmaxf(acc[jt][r], 0.0f);
                s += v * v;
            }
#pragma unroll
            for (int m = 1; m <= 8; m <<= 1) s += __shfl_xor(s, m);
            scl[r] = 1.0f / fmaxf(sqrtf(s), 1e-12f);
        }

#pragma unroll
        for (int r = 0; r < 4; ++r) {
            const int i = i0 + lGrp * 4 + r;
            if (i < N) {
#pragma unroll
                for (int jt = 0; jt < 8; ++jt) {
                    float v = fmaxf(acc[jt][r], 0.0f) * scl[r];
                    if (LAST) fOut[(size_t)i * 128 + jt * 16 + lRow] = v;
                    else      hOut[(size_t)i * 128 + jt * 16 + lRow] = f2h(v);
                }
            }
        }

        // readout: node2graph is sorted -> tiles almost always single-graph
        const int gFirst = n2g[i0 < N ? i0 : N - 1];
        const int gLast  = n2g[(i0 + 15) < N ? (i0 + 15) : N - 1];
        if (gFirst == gLast && i0 + 15 < N) {
#pragma unroll
            for (int jt = 0; jt < 8; ++jt) {
                float t = 0.f;
#pragma unroll
                for (int r = 0; r < 4; ++r) t += fmaxf(acc[jt][r], 0.0f) * scl[r];
                t += __shfl_xor(t, 16);
                t += __shfl_xor(t, 32);
                if (lane < 16)
                    unsafeAtomicAdd(&readout[(size_t)gFirst * 384 + layerOff + jt * 16 + lane], t);
            }
        } else {
#pragma unroll
            for (int r = 0; r < 4; ++r) {
                const int i = i0 + lGrp * 4 + r;
                if (i < N) {
                    const int g = n2g[i];
#pragma unroll
                    for (int jt = 0; jt < 8; ++jt) {
                        float v = fmaxf(acc[jt][r], 0.0f) * scl[r];
                        unsafeAtomicAdd(&readout[(size_t)g * 384 + layerOff + jt * 16 + lRow], v);
                    }
                }
            }
        }
    }
}

// ---------------------------------------------------------------------------
extern "C" void kernel_launch(void* const* d_in, const int* in_sizes, int n_in,
                              void* d_out, int out_size, void* d_ws, size_t ws_size,
                              hipStream_t stream)
{
    const int*   gate_type = (const int*)d_in[0];
    const int*   src  = (const int*)d_in[1];
    const int*   dst  = (const int*)d_in[2];
    const float* wE   = (const float*)d_in[3];
    const int*   n2g  = (const int*)d_in[4];
    const float* emb  = (const float*)d_in[5];
    const float* W1_0 = (const float*)d_in[6];
    const float* b1_0 = (const float*)d_in[7];
    const float* W2_0 = (const float*)d_in[8];
    const float* W1_1 = (const float*)d_in[9];
    const float* b1_1 = (const float*)d_in[10];
    const float* W2_1 = (const float*)d_in[11];
    const float* W1_2 = (const float*)d_in[12];
    const float* b1_2 = (const float*)d_in[13];
    const float* W2_2 = (const float*)d_in[14];

    const int N = in_sizes[0];
    const int E = in_sizes[1];

    // workspace carve-up (f16 h buffers + f16 transposed weights) ~77 MB
    char* ws = (char*)d_ws;
    size_t off = 0;
    auto alloc = [&](size_t bytes) { void* p = ws + off; off = (off + bytes + 255) & ~255ULL; return p; };
    _Float16* h0   = (_Float16*)alloc((size_t)N * 64 * 2);
    _Float16* h128 = (_Float16*)alloc((size_t)N * 128 * 2);
    _Float16* W1T0 = (_Float16*)alloc((size_t)128 * 96 * 2);
    _Float16* W1T1 = (_Float16*)alloc((size_t)128 * 160 * 2);
    _Float16* W1T2 = (_Float16*)alloc((size_t)128 * 160 * 2);
    _Float16* W2T0 = (_Float16*)alloc((size_t)128 * 192 * 2);
    _Float16* W2T1 = (_Float16*)alloc((size_t)128 * 256 * 2);
    _Float16* W2T2 = (_Float16*)alloc((size_t)128 * 256 * 2);

    float* hN      = (float*)d_out;                   // [N,128] scratch; final h lands here
    float* readout = (float*)d_out + (size_t)N * 128; // [G,384]

    const int eTiles = (E + 15) / 16;
    const int nTiles = (N + 15) / 16;

    embed_kernel<<<(N * 16 + 255) / 256, 256, 0, stream>>>(gate_type, emb, h0, N);
    wprep_kernel<<<(128 *  96 + 255) / 256, 256, 0, stream>>>(W1_0, W1T0,  67,  96);
    wprep_kernel<<<(128 * 160 + 255) / 256, 256, 0, stream>>>(W1_1, W1T1, 131, 160);
    wprep_kernel<<<(128 * 160 + 255) / 256, 256, 0, stream>>>(W1_2, W1T2, 131, 160);
    wprep_kernel<<<(128 * 192 + 255) / 256, 256, 0, stream>>>(W2_0, W2T0, 192, 192);
    wprep_kernel<<<(128 * 256 + 255) / 256, 256, 0, stream>>>(W2_1, W2T1, 256, 256);
    wprep_kernel<<<(128 * 256 + 255) / 256, 256, 0, stream>>>(W2_2, W2T2, 256, 256);

    hipMemsetAsync(d_out, 0, (size_t)out_size * 4, stream);   // hN layer-0 + readouts

    // layer 0
    edge_kernel<64><<<768, 256, 0, stream>>>(h0, W1T0, b1_0, src, dst, wE, hN, E, eTiles);
    node_kernel<64, false><<<512, 256, 0, stream>>>(h0, hN, W2T0, n2g, h128, nullptr, readout, N, nTiles, 0);
    hipMemsetAsync(d_out, 0, (size_t)N * 128 * 4, stream);
    // layer 1
    edge_kernel<128><<<768, 256, 0, stream>>>(h128, W1T1, b1_1, src, dst, wE, hN, E, eTiles);
    node_kernel<128, false><<<512, 256, 0, stream>>>(h128, hN, W2T1, n2g, h128, nullptr, readout, N, nTiles, 128);
    hipMemsetAsync(d_out, 0, (size_t)N * 128 * 4, stream);
    // layer 2 (node kernel writes final h fp32 in-place over hN = d_out)
    edge_kernel<128><<<768, 256, 0, stream>>>(h128, W1T2, b1_2, src, dst, wE, hN, E, eTiles);
    node_kernel<128, true><<<512, 256, 0, stream>>>(h128, hN, W2T2, n2g, nullptr, hN, readout, N, nTiles, 256);
}

// Round 2
// 1113.864 us; speedup vs baseline: 1.2284x; 1.2284x over previous
//
#include <hip/hip_runtime.h>
#include <hip/hip_bf16.h>
#include <hip/hip_fp16.h>

typedef _Float16 half8 __attribute__((ext_vector_type(8)));
typedef _Float16 half4 __attribute__((ext_vector_type(4)));
typedef float floatx4 __attribute__((ext_vector_type(4)));

__device__ __forceinline__ _Float16 f2h(float f) { return (_Float16)f; }

// ---------------------------------------------------------------------------
// counting-sort of edges by dst
// ---------------------------------------------------------------------------
__global__ void hist_kernel(const int* __restrict__ dst, int* __restrict__ cnt, int E)
{
    int e = blockIdx.x * 256 + threadIdx.x;
    if (e < E) atomicAdd(&cnt[dst[e]], 1);
}

__global__ void scan1_kernel(int* __restrict__ data, int n, int* __restrict__ blockSums)
{
    __shared__ int sm[256];
    const int t = threadIdx.x;
    const int base = blockIdx.x * 1024 + t * 4;
    int v[4]; int s = 0;
#pragma unroll
    for (int i = 0; i < 4; ++i) { v[i] = (base + i < n) ? data[base + i] : 0; s += v[i]; }
    sm[t] = s; __syncthreads();
#pragma unroll
    for (int off = 1; off < 256; off <<= 1) {
        int y = (t >= off) ? sm[t - off] : 0;
        __syncthreads();
        if (t >= off) sm[t] += y;
        __syncthreads();
    }
    int excl = sm[t] - s;
    if (t == 255) blockSums[blockIdx.x] = sm[255];
    int run = excl;
#pragma unroll
    for (int i = 0; i < 4; ++i) {
        if (base + i < n) data[base + i] = run;
        run += v[i];
    }
}

__global__ void scan2_kernel(int* __restrict__ blockSums, int nb)
{
    __shared__ int sm[256];
    const int t = threadIdx.x;
    int s = (t < nb) ? blockSums[t] : 0;
    sm[t] = s; __syncthreads();
#pragma unroll
    for (int off = 1; off < 256; off <<= 1) {
        int y = (t >= off) ? sm[t - off] : 0;
        __syncthreads();
        if (t >= off) sm[t] += y;
        __syncthreads();
    }
    if (t < nb) blockSums[t] = sm[t] - s;
}

__global__ void scan3_kernel(int* __restrict__ data, int n, const int* __restrict__ blockSums)
{
    const int base = blockIdx.x * 1024 + threadIdx.x * 4;
    const int add = blockSums[blockIdx.x];
#pragma unroll
    for (int i = 0; i < 4; ++i)
        if (base + i < n) data[base + i] += add;
}

__global__ void scatter_kernel(const int* __restrict__ src, const int* __restrict__ dst,
                               const float* __restrict__ w, int* __restrict__ cursor,
                               int* __restrict__ srcS, int* __restrict__ dstS,
                               half4* __restrict__ wS4, int E)
{
    int e = blockIdx.x * 256 + threadIdx.x;
    if (e >= E) return;
    int d = dst[e];
    int p = atomicAdd(&cursor[d], 1);
    srcS[p] = src[e];
    dstS[p] = d;
    half4 q;
    q[0] = f2h(w[(size_t)e * 3 + 0]);
    q[1] = f2h(w[(size_t)e * 3 + 1]);
    q[2] = f2h(w[(size_t)e * 3 + 2]);
    q[3] = (_Float16)1.0f;             // constant-1 slot -> bias via MFMA (k=131)
    wS4[p] = q;
}

// ---------------------------------------------------------------------------
// weight prep: W [K,128] fp32 -> out [128,KP] f16, optional bias at col 131
// ---------------------------------------------------------------------------
__global__ void wprep_kernel(const float* __restrict__ W, const float* __restrict__ bias,
                             _Float16* __restrict__ out, int K, int KP)
{
    int idx = blockIdx.x * 256 + threadIdx.x;
    if (idx >= 128 * KP) return;
    int f = idx / KP, k = idx % KP;
    float v = 0.0f;
    if (k < K) v = W[(size_t)k * 128 + f];
    else if (bias != nullptr && k == 131) v = bias[f];
    out[idx] = f2h(v);
}

// embW1b[g][f] = b1_0[f] + sum_k emb[g][k]*W1_0[k][f]   (30x128)
__global__ void embW1_kernel(const float* __restrict__ emb, const float* __restrict__ W1,
                             const float* __restrict__ b1, float* __restrict__ out, int NGT)
{
    int idx = blockIdx.x * 256 + threadIdx.x;
    if (idx >= NGT * 128) return;
    int g = idx >> 7, f = idx & 127;
    float s = b1[f];
    for (int k = 0; k < 64; ++k) s += emb[g * 64 + k] * W1[(size_t)k * 128 + f];
    out[idx] = s;
}

// embW2[g][f] = sum_k emb[g][k]*W2_0[k][f]  (rows 0..63 of W2_0)
__global__ void embW2_kernel(const float* __restrict__ emb, const float* __restrict__ W2,
                             float* __restrict__ out, int NGT)
{
    int idx = blockIdx.x * 256 + threadIdx.x;
    if (idx >= NGT * 128) return;
    int g = idx >> 7, f = idx & 127;
    float s = 0.0f;
    for (int k = 0; k < 64; ++k) s += emb[g * 64 + k] * W2[(size_t)k * 128 + f];
    out[idx] = s;
}

// ---------------------------------------------------------------------------
// edge layer 0 (no MFMA): t = relu(embW1b[gt[src]] + w@W1w); merged atomic add
// ---------------------------------------------------------------------------
__global__ void __launch_bounds__(256, 4)
edge0_kernel(const int* __restrict__ gt, const float* __restrict__ embW1b,
             const float* __restrict__ W1_0,
             const int* __restrict__ srcS, const int* __restrict__ dstS,
             const half4* __restrict__ wS4,
             float* __restrict__ hN, int E, int tilesPerWave, int eTiles)
{
    const int tid  = threadIdx.x;
    const int lane = tid & 63;
    const int wv   = tid >> 6;
    const int lRow = lane & 15;
    const int lGrp = lane >> 4;

    float w1w[3][8];
#pragma unroll
    for (int c = 0; c < 3; ++c)
#pragma unroll
        for (int jt = 0; jt < 8; ++jt)
            w1w[c][jt] = W1_0[(size_t)(64 + c) * 128 + jt * 16 + lRow];

    const int wave = blockIdx.x * 4 + wv;
    const int t0 = wave * tilesPerWave;
    const int t1 = min(t0 + tilesPerWave, eTiles);

    for (int tile = t0; tile < t1; ++tile) {
        const int e0 = tile * 16;
        int runD; float runV[8];
        {
            const int er = e0 + lGrp * 4;
            const bool v_ = er < E;
            const int ec = v_ ? er : (E - 1);
            runD = dstS[ec];
            const int g_t = gt[srcS[ec]];
            half4 q = wS4[ec];
            float w0 = (float)q[0], w1 = (float)q[1], w2 = (float)q[2];
#pragma unroll
            for (int jt = 0; jt < 8; ++jt) {
                float m = embW1b[(size_t)g_t * 128 + jt * 16 + lRow]
                        + w0 * w1w[0][jt] + w1 * w1w[1][jt] + w2 * w1w[2][jt];
                runV[jt] = v_ ? fmaxf(m, 0.0f) : 0.0f;
            }
        }
#pragma unroll
        for (int r = 1; r < 4; ++r) {
            const int er = e0 + lGrp * 4 + r;
            const bool v_ = er < E;
            const int ec = v_ ? er : (E - 1);
            const int d_ = dstS[ec];
            const int g_t = gt[srcS[ec]];
            half4 q = wS4[ec];
            float w0 = (float)q[0], w1 = (float)q[1], w2 = (float)q[2];
            float vr[8];
#pragma unroll
            for (int jt = 0; jt < 8; ++jt) {
                float m = embW1b[(size_t)g_t * 128 + jt * 16 + lRow]
                        + w0 * w1w[0][jt] + w1 * w1w[1][jt] + w2 * w1w[2][jt];
                vr[jt] = v_ ? fmaxf(m, 0.0f) : 0.0f;
            }
            if (d_ == runD) {
#pragma unroll
                for (int jt = 0; jt < 8; ++jt) runV[jt] += vr[jt];
            } else {
                float* dp = hN + (size_t)runD * 128 + lRow;
#pragma unroll
                for (int jt = 0; jt < 8; ++jt)
                    if (runV[jt] > 0.0f) unsafeAtomicAdd(dp + jt * 16, runV[jt]);
                runD = d_;
#pragma unroll
                for (int jt = 0; jt < 8; ++jt) runV[jt] = vr[jt];
            }
        }
        float* dp = hN + (size_t)runD * 128 + lRow;
#pragma unroll
        for (int jt = 0; jt < 8; ++jt)
            if (runV[jt] > 0.0f) unsafeAtomicAdd(dp + jt * 16, runV[jt]);
    }
}

// ---------------------------------------------------------------------------
// edge layers 1,2 (MFMA): t = relu(cat(h[src],w,1)@W1T'); merged atomic add
// ---------------------------------------------------------------------------
__global__ void __launch_bounds__(256, 3)
edge_mfma_kernel(const _Float16* __restrict__ hA,   // [N,128]
                 const _Float16* __restrict__ W1T,  // [128,160] (w rows + bias at 131)
                 const int* __restrict__ srcS, const int* __restrict__ dstS,
                 const half4* __restrict__ wS4,
                 float* __restrict__ hN, int E, int tilesPerWave, int eTiles)
{
    constexpr int KPAD = 160, KC = 5, SPR = 20, LDSK = 192;
    __shared__ __align__(16) _Float16 lds[128 * LDSK];

    const int tid = threadIdx.x;
    for (int s = tid; s < 128 * SPR; s += 256) {
        const int row = s / SPR, seg = s % SPR;
        half8 v = *(const half8*)(W1T + (size_t)row * KPAD + seg * 8);
        *(half8*)(&lds[row * LDSK + ((seg ^ (row & 7)) * 8)]) = v;
    }
    __syncthreads();

    const int lane = tid & 63;
    const int wv   = tid >> 6;
    const int lRow = lane & 15;
    const int lGrp = lane >> 4;

    const int wave = blockIdx.x * 4 + wv;
    const int t0 = wave * tilesPerWave;
    const int t1 = min(t0 + tilesPerWave, eTiles);

    for (int tile = t0; tile < t1; ++tile) {
        const int e0 = tile * 16;
        const int eA = min(e0 + lRow, E - 1);
        const int s_ = srcS[eA];

        half8 afrag[KC];
#pragma unroll
        for (int kc = 0; kc < 4; ++kc)
            afrag[kc] = *(const half8*)(hA + (size_t)s_ * 128 + kc * 32 + lGrp * 8);
        {
            half8 aw = {};
            if (lGrp == 0) {
                half4 q = wS4[eA];
                aw[0] = q[0]; aw[1] = q[1]; aw[2] = q[2]; aw[3] = q[3];  // w0,w1,w2,1.0
            }
            afrag[4] = aw;
        }

        floatx4 acc[8] = {};
#pragma unroll
        for (int jt = 0; jt < 8; ++jt) {
            const int rb = (jt * 16 + lRow) * LDSK;
            const int sw = (jt * 16 + lRow) & 7;
#pragma unroll
            for (int kc = 0; kc < KC; ++kc) {
                const int seg = kc * 4 + lGrp;
                half8 bfrag = *(const half8*)(&lds[rb + ((seg ^ sw) * 8)]);
                acc[jt] = __builtin_amdgcn_mfma_f32_16x16x32_f16(afrag[kc], bfrag, acc[jt], 0, 0, 0);
            }
        }

        // in-lane run merge over the 4 rows, then atomics (sorted dst)
        int runD; float runV[8];
        {
            const int er = e0 + lGrp * 4;
            const bool v_ = er < E;
            runD = dstS[v_ ? er : (E - 1)];
#pragma unroll
            for (int jt = 0; jt < 8; ++jt) runV[jt] = v_ ? fmaxf(acc[jt][0], 0.0f) : 0.0f;
        }
#pragma unroll
        for (int r = 1; r < 4; ++r) {
            const int er = e0 + lGrp * 4 + r;
            const bool v_ = er < E;
            const int d_ = dstS[v_ ? er : (E - 1)];
            if (d_ == runD) {
#pragma unroll
                for (int jt = 0; jt < 8; ++jt)
                    runV[jt] += v_ ? fmaxf(acc[jt][r], 0.0f) : 0.0f;
            } else {
                float* dp = hN + (size_t)runD * 128 + lRow;
#pragma unroll
                for (int jt = 0; jt < 8; ++jt)
                    if (runV[jt] > 0.0f) unsafeAtomicAdd(dp + jt * 16, runV[jt]);
                runD = d_;
#pragma unroll
                for (int jt = 0; jt < 8; ++jt)
                    runV[jt] = v_ ? fmaxf(acc[jt][r], 0.0f) : 0.0f;
            }
        }
        float* dp = hN + (size_t)runD * 128 + lRow;
#pragma unroll
        for (int jt = 0; jt < 8; ++jt)
            if (runV[jt] > 0.0f) unsafeAtomicAdd(dp + jt * 16, runV[jt]);
    }
}

// ---------------------------------------------------------------------------
// node kernel: h = normalize(relu([h,]hN @ W2 [+ embW2[gt]])); readout
// ---------------------------------------------------------------------------
template<bool L0, bool LAST>
__global__ void __launch_bounds__(256, 2)
node_kernel(const _Float16* __restrict__ hA,    // [N,128] (unused if L0)
            const float* __restrict__ hN,       // [N,128] fp32
            const _Float16* __restrict__ W2T,   // [128,K2]
            const float* __restrict__ embW2,    // [30,128] (L0 only)
            const int* __restrict__ gt,         // (L0 only)
            const int* __restrict__ n2g,
            _Float16* __restrict__ hOut,        // if !LAST
            float* __restrict__ fOut,           // if LAST (aliases hN)
            float* __restrict__ readout,
            int N, int nTiles, int layerOff)
{
    constexpr int K2  = L0 ? 128 : 256;
    constexpr int KCA = L0 ? 0 : 4;
    constexpr int KC  = K2 / 32;
    constexpr int SPR = K2 / 8;
    __shared__ __align__(16) _Float16 lds[128 * K2];

    const int tid = threadIdx.x;
    for (int s = tid; s < 128 * SPR; s += 256) {
        const int row = s / SPR, seg = s % SPR;
        half8 v = *(const half8*)(W2T + (size_t)row * K2 + seg * 8);
        *(half8*)(&lds[row * K2 + ((seg ^ (row & 7)) * 8)]) = v;
    }
    __syncthreads();

    const int lane = tid & 63;
    const int wv   = tid >> 6;
    const int lRow = lane & 15;
    const int lGrp = lane >> 4;

    for (int tile = blockIdx.x * 4 + wv; tile < nTiles; tile += gridDim.x * 4) {
        const int i0 = tile * 16;
        const int iA = min(i0 + lRow, N - 1);

        half8 afrag[KC];
#pragma unroll
        for (int kc = 0; kc < KCA; ++kc)
            afrag[kc] = *(const half8*)(hA + (size_t)iA * 128 + kc * 32 + lGrp * 8);
#pragma unroll
        for (int kc = KCA; kc < KC; ++kc) {
            const float* p = hN + (size_t)iA * 128 + (kc - KCA) * 32 + lGrp * 8;
            floatx4 f0 = *(const floatx4*)(p);
            floatx4 f1 = *(const floatx4*)(p + 4);
            half8 a;
#pragma unroll
            for (int i = 0; i < 4; ++i) { a[i] = f2h(f0[i]); a[i + 4] = f2h(f1[i]); }
            afrag[kc] = a;
        }

        floatx4 acc[8] = {};
#pragma unroll
        for (int jt = 0; jt < 8; ++jt) {
            const int rb = (jt * 16 + lRow) * K2;
            const int sw = (jt * 16 + lRow) & 7;
#pragma unroll
            for (int kc = 0; kc < KC; ++kc) {
                const int seg = kc * 4 + lGrp;
                half8 bfrag = *(const half8*)(&lds[rb + ((seg ^ sw) * 8)]);
                acc[jt] = __builtin_amdgcn_mfma_f32_16x16x32_f16(afrag[kc], bfrag, acc[jt], 0, 0, 0);
            }
        }

        if (L0) {   // + emb[gt]@W2_0[:64] contribution (per-row bias gather)
#pragma unroll
            for (int r = 0; r < 4; ++r) {
                const int i = min(i0 + lGrp * 4 + r, N - 1);
                const int g_t = gt[i];
#pragma unroll
                for (int jt = 0; jt < 8; ++jt)
                    acc[jt][r] += embW2[(size_t)g_t * 128 + jt * 16 + lRow];
            }
        }

        float scl[4];
#pragma unroll
        for (int r = 0; r < 4; ++r) {
            float s = 0.f;
#pragma unroll
            for (int jt = 0; jt < 8; ++jt) {
                float v = fmaxf(acc[jt][r], 0.0f);
                s += v * v;
            }
#pragma unroll
            for (int m = 1; m <= 8; m <<= 1) s += __shfl_xor(s, m);
            scl[r] = 1.0f / fmaxf(sqrtf(s), 1e-12f);
        }

#pragma unroll
        for (int r = 0; r < 4; ++r) {
            const int i = i0 + lGrp * 4 + r;
            if (i < N) {
#pragma unroll
                for (int jt = 0; jt < 8; ++jt) {
                    float v = fmaxf(acc[jt][r], 0.0f) * scl[r];
                    if (LAST) fOut[(size_t)i * 128 + jt * 16 + lRow] = v;
                    else      hOut[(size_t)i * 128 + jt * 16 + lRow] = f2h(v);
                }
            }
        }

        const int gFirst = n2g[min(i0, N - 1)];
        const int gLast  = n2g[min(i0 + 15, N - 1)];
        if (gFirst == gLast && i0 + 15 < N) {
#pragma unroll
            for (int jt = 0; jt < 8; ++jt) {
                float t = 0.f;
#pragma unroll
                for (int r = 0; r < 4; ++r) t += fmaxf(acc[jt][r], 0.0f) * scl[r];
                t += __shfl_xor(t, 16);
                t += __shfl_xor(t, 32);
                if (lane < 16)
                    unsafeAtomicAdd(&readout[(size_t)gFirst * 384 + layerOff + jt * 16 + lane], t);
            }
        } else {
#pragma unroll
            for (int r = 0; r < 4; ++r) {
                const int i = i0 + lGrp * 4 + r;
                if (i < N) {
                    const int g = n2g[i];
#pragma unroll
                    for (int jt = 0; jt < 8; ++jt) {
                        float v = fmaxf(acc[jt][r], 0.0f) * scl[r];
                        unsafeAtomicAdd(&readout[(size_t)g * 384 + layerOff + jt * 16 + lRow], v);
                    }
                }
            }
        }
    }
}

// ---------------------------------------------------------------------------
extern "C" void kernel_launch(void* const* d_in, const int* in_sizes, int n_in,
                              void* d_out, int out_size, void* d_ws, size_t ws_size,
                              hipStream_t stream)
{
    const int*   gate_type = (const int*)d_in[0];
    const int*   src  = (const int*)d_in[1];
    const int*   dst  = (const int*)d_in[2];
    const float* wE   = (const float*)d_in[3];
    const int*   n2g  = (const int*)d_in[4];
    const float* emb  = (const float*)d_in[5];
    const float* W1_0 = (const float*)d_in[6];
    const float* b1_0 = (const float*)d_in[7];
    const float* W2_0 = (const float*)d_in[8];
    const float* W1_1 = (const float*)d_in[9];
    const float* b1_1 = (const float*)d_in[10];
    const float* W2_1 = (const float*)d_in[11];
    const float* W1_2 = (const float*)d_in[12];
    const float* b1_2 = (const float*)d_in[13];
    const float* W2_2 = (const float*)d_in[14];

    const int N = in_sizes[0];
    const int E = in_sizes[1];
    const int NGT = in_sizes[5] / 64;

    char* ws = (char*)d_ws;
    size_t off = 0;
    auto alloc = [&](size_t bytes) { void* p = ws + off; off = (off + bytes + 255) & ~255ULL; return p; };
    _Float16* hBuf  = (_Float16*)alloc((size_t)N * 128 * 2);
    int*      srcS  = (int*)alloc((size_t)E * 4);
    int*      dstS  = (int*)alloc((size_t)E * 4);
    half4*    wS4   = (half4*)alloc((size_t)E * 8);
    int*      cnt   = (int*)alloc((size_t)N * 4);
    int*      bSums = (int*)alloc(256 * 4);
    _Float16* W1T1  = (_Float16*)alloc((size_t)128 * 160 * 2);
    _Float16* W1T2  = (_Float16*)alloc((size_t)128 * 160 * 2);
    _Float16* W2T0  = (_Float16*)alloc((size_t)128 * 128 * 2);
    _Float16* W2T1  = (_Float16*)alloc((size_t)128 * 256 * 2);
    _Float16* W2T2  = (_Float16*)alloc((size_t)128 * 256 * 2);
    float*    eW1b  = (float*)alloc((size_t)NGT * 128 * 4);
    float*    eW2   = (float*)alloc((size_t)NGT * 128 * 4);

    float* hN      = (float*)d_out;                    // [N,128]; final h lands here
    float* readout = (float*)d_out + (size_t)N * 128;  // [G,384]

    const int eTiles = (E + 15) / 16;
    const int nTiles = (N + 15) / 16;
    const int EB = 768;                 // edge-kernel blocks
    const int nWaves = EB * 4;
    const int tpw = (eTiles + nWaves - 1) / nWaves;
    const int nb = (N + 1023) / 1024;   // scan blocks (must be <= 256)

    // ---- sort edges by dst ----
    hipMemsetAsync(d_out, 0, (size_t)out_size * 4, stream);   // hN layer-0 + readout
    hipMemsetAsync(cnt, 0, (size_t)N * 4, stream);
    hist_kernel<<<(E + 255) / 256, 256, 0, stream>>>(dst, cnt, E);
    scan1_kernel<<<nb, 256, 0, stream>>>(cnt, N, bSums);
    scan2_kernel<<<1, 256, 0, stream>>>(bSums, nb);
    scan3_kernel<<<nb, 256, 0, stream>>>(cnt, N, bSums);
    scatter_kernel<<<(E + 255) / 256, 256, 0, stream>>>(src, dst, wE, cnt, srcS, dstS, wS4, E);

    // ---- weight prep ----
    embW1_kernel<<<(NGT * 128 + 255) / 256, 256, 0, stream>>>(emb, W1_0, b1_0, eW1b, NGT);
    embW2_kernel<<<(NGT * 128 + 255) / 256, 256, 0, stream>>>(emb, W2_0, eW2, NGT);
    wprep_kernel<<<(128 * 160 + 255) / 256, 256, 0, stream>>>(W1_1, b1_1, W1T1, 131, 160);
    wprep_kernel<<<(128 * 160 + 255) / 256, 256, 0, stream>>>(W1_2, b1_2, W1T2, 131, 160);
    wprep_kernel<<<(128 * 128 + 255) / 256, 256, 0, stream>>>(W2_0 + (size_t)64 * 128, nullptr, W2T0, 128, 128);
    wprep_kernel<<<(128 * 256 + 255) / 256, 256, 0, stream>>>(W2_1, nullptr, W2T1, 256, 256);
    wprep_kernel<<<(128 * 256 + 255) / 256, 256, 0, stream>>>(W2_2, nullptr, W2T2, 256, 256);

    // ---- layer 0 ----
    edge0_kernel<<<EB, 256, 0, stream>>>(gate_type, eW1b, W1_0, srcS, dstS, wS4, hN, E, tpw, eTiles);
    node_kernel<true, false><<<512, 256, 0, stream>>>(nullptr, hN, W2T0, eW2, gate_type, n2g,
                                                      hBuf, nullptr, readout, N, nTiles, 0);
    hipMemsetAsync(d_out, 0, (size_t)N * 128 * 4, stream);
    // ---- layer 1 ----
    edge_mfma_kernel<<<EB, 256, 0, stream>>>(hBuf, W1T1, srcS, dstS, wS4, hN, E, tpw, eTiles);
    node_kernel<false, false><<<512, 256, 0, stream>>>(hBuf, hN, W2T1, nullptr, nullptr, n2g,
                                                       hBuf, nullptr, readout, N, nTiles, 128);
    hipMemsetAsync(d_out, 0, (size_t)N * 128 * 4, stream);
    // ---- layer 2 (node writes final fp32 h in place over hN) ----
    edge_mfma_kernel<<<EB, 256, 0, stream>>>(hBuf, W1T2, srcS, dstS, wS4, hN, E, tpw, eTiles);
    node_kernel<false, true><<<512, 256, 0, stream>>>(hBuf, hN, W2T2, nullptr, nullptr, n2g,
                                                      nullptr, hN, readout, N, nTiles, 256);
}